// Round 1
// baseline (3711.126 us; speedup 1.0000x reference)
//
#include <hip/hip_runtime.h>
#include <hip/hip_bf16.h>
#include <math.h>

#define B 4
#define S 2048
#define H 4
#define DK 64
#define DM 256

// ---------------------------------------------------------------------------
// K1: per-head q/k projections + shared v projection.
// One block per (b,s) token row; 256 threads = H*DK outputs for q/k.
// qs/ks layout: [B,H,S,DK]; vs layout: [B,S,DK].
// ---------------------------------------------------------------------------
__global__ __launch_bounds__(256) void proj_kernel(
    const float* __restrict__ q, const float* __restrict__ k,
    const float* __restrict__ v,
    const float* __restrict__ Wq, const float* __restrict__ Wk,
    const float* __restrict__ Wv,
    float* __restrict__ qs, float* __restrict__ ks, float* __restrict__ vs) {
  const int bs = blockIdx.x;  // b*S + s
  const int tid = threadIdx.x;
  __shared__ float qrow[DM], krow[DM], vrow[DM];
  qrow[tid] = q[(size_t)bs * DM + tid];
  krow[tid] = k[(size_t)bs * DM + tid];
  vrow[tid] = v[(size_t)bs * DM + tid];
  __syncthreads();
  const int h = tid >> 6, e = tid & 63;
  const float* wq = Wq + (size_t)(h * DK + e) * DM;
  const float* wk = Wk + (size_t)(h * DK + e) * DM;
  float aq = 0.f, ak = 0.f;
#pragma unroll 8
  for (int d = 0; d < DM; ++d) {
    aq = fmaf(qrow[d], wq[d], aq);
    ak = fmaf(krow[d], wk[d], ak);
  }
  const int b = bs >> 11, s = bs & (S - 1);
  qs[(size_t)((b * H + h) * S + s) * DK + e] = aq;
  ks[(size_t)((b * H + h) * S + s) * DK + e] = ak;
  if (h == 0) {
    const float* wv = Wv + (size_t)e * DM;
    float av = 0.f;
#pragma unroll 8
    for (int d = 0; d < DM; ++d) av = fmaf(vrow[d], wv[d], av);
    vs[(size_t)bs * DK + e] = av;
  }
}

// ---------------------------------------------------------------------------
// K2: attention. One block per (b,h,s) query row.
// Scores row staged in LDS (8 KB), softmax via wave shuffles + LDS combine,
// coalesced float4 write of the normalized row into attn_out[b,s,h,:],
// then PV with 4 thread-groups of 64 lanes (coalesced vs reads).
// ---------------------------------------------------------------------------
__global__ __launch_bounds__(256) void attn_kernel(
    const float* __restrict__ qs, const float* __restrict__ ks,
    const float* __restrict__ vs,
    float* __restrict__ attn_out, float* __restrict__ heads) {
  const int idx = blockIdx.x;  // ((b*H + h)*S + s)
  const int s = idx & (S - 1);
  const int h = (idx >> 11) & (H - 1);
  const int b = idx >> 13;
  const int tid = threadIdx.x;

  __shared__ float p[S];
  __shared__ float qrow[DK];
  __shared__ float red[4];
  __shared__ float opart[256];

  if (tid < DK) qrow[tid] = qs[(size_t)((b * H + h) * S + s) * DK + tid];
  __syncthreads();

  const float* ksb = ks + (size_t)(b * H + h) * S * DK;
  float lmax = -INFINITY;
  for (int t = tid; t < S; t += 256) {
    const float4* kr = (const float4*)(ksb + (size_t)t * DK);
    float acc = 0.f;
#pragma unroll
    for (int i = 0; i < DK / 4; ++i) {
      float4 kv = kr[i];
      acc = fmaf(qrow[4 * i + 0], kv.x, acc);
      acc = fmaf(qrow[4 * i + 1], kv.y, acc);
      acc = fmaf(qrow[4 * i + 2], kv.z, acc);
      acc = fmaf(qrow[4 * i + 3], kv.w, acc);
    }
    acc *= 0.125f;  // 1/sqrt(64)
    p[t] = acc;
    lmax = fmaxf(lmax, acc);
  }
  // block-wide max
#pragma unroll
  for (int off = 32; off; off >>= 1) lmax = fmaxf(lmax, __shfl_down(lmax, off, 64));
  if ((tid & 63) == 0) red[tid >> 6] = lmax;
  __syncthreads();
  const float m = fmaxf(fmaxf(red[0], red[1]), fmaxf(red[2], red[3]));
  __syncthreads();  // red reused below

  float lsum = 0.f;
  for (int t = tid; t < S; t += 256) {
    float ex = __expf(p[t] - m);
    p[t] = ex;
    lsum += ex;
  }
#pragma unroll
  for (int off = 32; off; off >>= 1) lsum += __shfl_down(lsum, off, 64);
  if ((tid & 63) == 0) red[tid >> 6] = lsum;
  __syncthreads();
  const float inv = 1.f / (red[0] + red[1] + red[2] + red[3]);

  // write normalized attention row: attn_out[b, s, h, :] (contiguous in t)
  float* arow = attn_out + (((size_t)(b * S + s)) * H + h) * S;
  for (int t4 = tid; t4 < S / 4; t4 += 256) {
    float4 vout = {p[4 * t4 + 0] * inv, p[4 * t4 + 1] * inv,
                   p[4 * t4 + 2] * inv, p[4 * t4 + 3] * inv};
    ((float4*)arow)[t4] = vout;
  }

  // PV: group g of 64 lanes handles t in [g*512,(g+1)*512); lane e = output dim
  const int e = tid & 63, g = tid >> 6;
  const float* vsb = vs + (size_t)b * S * DK;
  float o = 0.f;
  for (int t = g * (S / 4); t < (g + 1) * (S / 4); ++t)
    o = fmaf(p[t], vsb[(size_t)t * DK + e], o);
  opart[tid] = o;
  __syncthreads();
  if (tid < DK) {
    float sum = (opart[tid] + opart[64 + tid] + opart[128 + tid] + opart[192 + tid]) * inv;
    heads[(size_t)((b * H + h) * S + s) * DK + tid] = sum;
  }
}

// ---------------------------------------------------------------------------
// K3: mean over heads + output projection. One block per (b,s) token.
// ---------------------------------------------------------------------------
__global__ __launch_bounds__(256) void out_kernel(
    const float* __restrict__ heads, const float* __restrict__ Wh,
    float* __restrict__ out) {
  const int bs = blockIdx.x;
  const int b = bs >> 11, s = bs & (S - 1);
  const int tid = threadIdx.x;
  __shared__ float pooled[DK];
  if (tid < DK) {
    const float* hb = heads + ((size_t)(b * H) * S + s) * DK + tid;
    float acc = 0.f;
#pragma unroll
    for (int hh = 0; hh < H; ++hh) acc += hb[(size_t)hh * S * DK];
    pooled[tid] = acc * 0.25f;  // mean over H=4 heads
  }
  __syncthreads();
  const float* wh = Wh + (size_t)tid * DK;
  float acc = 0.f;
#pragma unroll
  for (int e2 = 0; e2 < DK; ++e2) acc = fmaf(pooled[e2], wh[e2], acc);
  out[(size_t)bs * DM + tid] = acc;
}

extern "C" void kernel_launch(void* const* d_in, const int* in_sizes, int n_in,
                              void* d_out, int out_size, void* d_ws, size_t ws_size,
                              hipStream_t stream) {
  const float* q = (const float*)d_in[0];
  const float* k = (const float*)d_in[1];
  const float* v = (const float*)d_in[2];
  const float* Wq = (const float*)d_in[3];
  const float* Wk = (const float*)d_in[4];
  const float* Wv = (const float*)d_in[5];
  const float* Wh = (const float*)d_in[6];

  float* out = (float*)d_out;                     // [B,S,DM]
  float* attn_out = out + (size_t)B * S * DM;     // [B,S,H,S]

  float* ws = (float*)d_ws;
  float* qs = ws;                                 // B*H*S*DK
  float* ksp = qs + (size_t)B * H * S * DK;       // B*H*S*DK
  float* vsp = ksp + (size_t)B * H * S * DK;      // B*S*DK
  float* heads = vsp + (size_t)B * S * DK;        // B*H*S*DK

  proj_kernel<<<B * S, 256, 0, stream>>>(q, k, v, Wq, Wk, Wv, qs, ksp, vsp);
  attn_kernel<<<B * H * S, 256, 0, stream>>>(qs, ksp, vsp, attn_out, heads);
  out_kernel<<<B * S, 256, 0, stream>>>(heads, Wh, out);
}

// Round 2
// 877.649 us; speedup vs baseline: 4.2285x; 4.2285x over previous
//
#include <hip/hip_runtime.h>
#include <hip/hip_bf16.h>
#include <math.h>

#define B 4
#define S 2048
#define H 4
#define DK 64
#define DM 256
#define PSTR 40  // LDS strip stride in bf16 elems: 80B -> conflict-free b128 reads, 16B-aligned

using bf16x8 = __attribute__((ext_vector_type(8))) short;
using f32x4 = __attribute__((ext_vector_type(4))) float;

__device__ inline ushort f2b(float f) {
  __hip_bfloat16 h = __float2bfloat16(f);
  ushort u; __builtin_memcpy(&u, &h, 2); return u;
}
__device__ inline float b2f(ushort u) {
  __hip_bfloat16 h; __builtin_memcpy(&h, &u, 2); return __bfloat162float(h);
}
__device__ inline bf16x8 ld8(const ushort* p) {
  return *reinterpret_cast<const bf16x8*>(p);
}
#define MFMA(a, b, c) __builtin_amdgcn_mfma_f32_16x16x32_bf16((a), (b), (c), 0, 0, 0)

// ---------------------------------------------------------------------------
// K1: projections -> split-bf16 qs/ks ([B,H,S,DK] hi+lo) and bf16 vT [B,DK,S].
// One block per (b,s) token; float4 weight loads.
// ---------------------------------------------------------------------------
__global__ __launch_bounds__(256) void proj_kernel(
    const float* __restrict__ q, const float* __restrict__ k,
    const float* __restrict__ v,
    const float* __restrict__ Wq, const float* __restrict__ Wk,
    const float* __restrict__ Wv,
    ushort* __restrict__ qhi, ushort* __restrict__ qlo,
    ushort* __restrict__ khi, ushort* __restrict__ klo,
    ushort* __restrict__ vT) {
  const int bs = blockIdx.x;
  const int tid = threadIdx.x;
  __shared__ __align__(16) float qrow[DM], krow[DM], vrow[DM];
  qrow[tid] = q[(size_t)bs * DM + tid];
  krow[tid] = k[(size_t)bs * DM + tid];
  vrow[tid] = v[(size_t)bs * DM + tid];
  __syncthreads();
  const int h = tid >> 6, e = tid & 63;
  const float4* wq4 = (const float4*)(Wq + (size_t)(h * DK + e) * DM);
  const float4* wk4 = (const float4*)(Wk + (size_t)(h * DK + e) * DM);
  const float4* q4 = (const float4*)qrow;
  const float4* k4 = (const float4*)krow;
  float aq = 0.f, ak = 0.f;
#pragma unroll 8
  for (int d = 0; d < DM / 4; ++d) {
    float4 a = wq4[d], xq = q4[d];
    aq = fmaf(a.x, xq.x, aq); aq = fmaf(a.y, xq.y, aq);
    aq = fmaf(a.z, xq.z, aq); aq = fmaf(a.w, xq.w, aq);
    float4 bb = wk4[d], xk = k4[d];
    ak = fmaf(bb.x, xk.x, ak); ak = fmaf(bb.y, xk.y, ak);
    ak = fmaf(bb.z, xk.z, ak); ak = fmaf(bb.w, xk.w, ak);
  }
  const int b = bs >> 11, s = bs & (S - 1);
  const size_t idx = ((size_t)((b * H + h) * S + s)) * DK + e;
  ushort qh16 = f2b(aq);
  qhi[idx] = qh16; qlo[idx] = f2b(aq - b2f(qh16));
  ushort kh16 = f2b(ak);
  khi[idx] = kh16; klo[idx] = f2b(ak - b2f(kh16));
  if (h == 0) {
    const float4* wv4 = (const float4*)(Wv + (size_t)e * DM);
    const float4* v4 = (const float4*)vrow;
    float av = 0.f;
#pragma unroll 8
    for (int d = 0; d < DM / 4; ++d) {
      float4 a = wv4[d], xv = v4[d];
      av = fmaf(a.x, xv.x, av); av = fmaf(a.y, xv.y, av);
      av = fmaf(a.z, xv.z, av); av = fmaf(a.w, xv.w, av);
    }
    vT[((size_t)b * DK + e) * S + s] = f2b(av);
  }
}

// ---------------------------------------------------------------------------
// K2: attention via MFMA. One wave = 16 query rows of one (b,h).
// Sweep 1: online (max, sumexp) over all 2048 keys (split-bf16 QK^T, 3 MFMAs
// per k-half for near-fp32 scores). Sweep 2: recompute scores, normalize,
// write attn fp32, bounce P through wave-private LDS strip to A-fragment
// layout, accumulate PV with bf16 MFMA from transposed V (vT, L2-resident).
// No block-level barriers: waves fully independent.
// ---------------------------------------------------------------------------
#define QK_CHUNK(T0, ACC0, ACC1)                                              \
  do {                                                                        \
    const ushort* kh_ = kbh + ((T0) + l15) * DK + 8 * g;                      \
    const ushort* kl_ = kbl + ((T0) + l15) * DK + 8 * g;                      \
    bf16x8 bh0 = ld8(kh_), bh1 = ld8(kh_ + 32);                               \
    bf16x8 bl0 = ld8(kl_), bl1 = ld8(kl_ + 32);                               \
    bf16x8 ch0 = ld8(kh_ + 16 * DK), ch1 = ld8(kh_ + 16 * DK + 32);           \
    bf16x8 cl0 = ld8(kl_ + 16 * DK), cl1 = ld8(kl_ + 16 * DK + 32);           \
    ACC0 = MFMA(aqh0, bh0, ACC0); ACC0 = MFMA(aqh1, bh1, ACC0);               \
    ACC0 = MFMA(aql0, bh0, ACC0); ACC0 = MFMA(aql1, bh1, ACC0);               \
    ACC0 = MFMA(aqh0, bl0, ACC0); ACC0 = MFMA(aqh1, bl1, ACC0);               \
    ACC1 = MFMA(aqh0, ch0, ACC1); ACC1 = MFMA(aqh1, ch1, ACC1);               \
    ACC1 = MFMA(aql0, ch0, ACC1); ACC1 = MFMA(aql1, ch1, ACC1);               \
    ACC1 = MFMA(aqh0, cl0, ACC1); ACC1 = MFMA(aqh1, cl1, ACC1);               \
  } while (0)

__global__ __launch_bounds__(256) void attn_kernel(
    const ushort* __restrict__ qhi, const ushort* __restrict__ qlo,
    const ushort* __restrict__ khi, const ushort* __restrict__ klo,
    const ushort* __restrict__ vT,
    float* __restrict__ attn_out, float* __restrict__ heads) {
  __shared__ __align__(16) ushort pstrip[4][16 * PSTR];
  const int wid = threadIdx.x >> 6;
  const int lane = threadIdx.x & 63;
  const int l15 = lane & 15, g = lane >> 4;
  const int bid = blockIdx.x;
  // XCD-aware swizzle: grid 512 = 8 XCDs x 64 contiguous blocks
  const int swz = (bid & 7) * 64 + (bid >> 3);
  const int wave = swz * 4 + wid;  // 0..2047
  const int st = wave & 127;
  const int h = (wave >> 7) & 3;
  const int b = wave >> 9;
  const int row0 = st * 16;

  const size_t bh = (size_t)(b * H + h);
  const ushort* qbh = qhi + (bh * S + row0 + l15) * DK;
  const ushort* qbl = qlo + (bh * S + row0 + l15) * DK;
  const bf16x8 aqh0 = ld8(qbh + 8 * g), aqh1 = ld8(qbh + 32 + 8 * g);
  const bf16x8 aql0 = ld8(qbl + 8 * g), aql1 = ld8(qbl + 32 + 8 * g);
  const ushort* kbh = khi + bh * S * DK;
  const ushort* kbl = klo + bh * S * DK;

  // ---- sweep 1: online row max + sumexp (rows 4g+r, cols spread on l15) ----
  float m4[4] = {-1e30f, -1e30f, -1e30f, -1e30f};
  float s4[4] = {0.f, 0.f, 0.f, 0.f};
#pragma unroll 2
  for (int t0 = 0; t0 < S; t0 += 32) {
    f32x4 acc0 = {0.f, 0.f, 0.f, 0.f}, acc1 = {0.f, 0.f, 0.f, 0.f};
    QK_CHUNK(t0, acc0, acc1);
#pragma unroll
    for (int r = 0; r < 4; ++r) {
      float pm = fmaxf(acc0[r], acc1[r]);
      pm = fmaxf(pm, __shfl_xor(pm, 1));
      pm = fmaxf(pm, __shfl_xor(pm, 2));
      pm = fmaxf(pm, __shfl_xor(pm, 4));
      pm = fmaxf(pm, __shfl_xor(pm, 8));
      float mn = fmaxf(m4[r], pm);
      float es = __expf((acc0[r] - mn) * 0.125f) + __expf((acc1[r] - mn) * 0.125f);
      es += __shfl_xor(es, 1);
      es += __shfl_xor(es, 2);
      es += __shfl_xor(es, 4);
      es += __shfl_xor(es, 8);
      s4[r] = s4[r] * __expf((m4[r] - mn) * 0.125f) + es;
      m4[r] = mn;
    }
  }
  float inv4[4];
#pragma unroll
  for (int r = 0; r < 4; ++r) inv4[r] = 1.f / s4[r];

  // ---- sweep 2: recompute, normalize, write attn, PV ----
  f32x4 hacc[4] = {{0.f, 0.f, 0.f, 0.f}, {0.f, 0.f, 0.f, 0.f},
                   {0.f, 0.f, 0.f, 0.f}, {0.f, 0.f, 0.f, 0.f}};
  const ushort* vb_b = vT + (size_t)b * DK * S;
  float* arows[4];
#pragma unroll
  for (int r = 0; r < 4; ++r)
    arows[r] = attn_out + ((size_t)(b * S + row0 + 4 * g + r) * H + h) * S;
  ushort* strip = pstrip[wid];

#pragma unroll 2
  for (int t0 = 0; t0 < S; t0 += 32) {
    f32x4 acc0 = {0.f, 0.f, 0.f, 0.f}, acc1 = {0.f, 0.f, 0.f, 0.f};
    QK_CHUNK(t0, acc0, acc1);
#pragma unroll
    for (int r = 0; r < 4; ++r) {
      float p0 = __expf((acc0[r] - m4[r]) * 0.125f) * inv4[r];
      float p1 = __expf((acc1[r] - m4[r]) * 0.125f) * inv4[r];
      arows[r][t0 + l15] = p0;
      arows[r][t0 + 16 + l15] = p1;
      strip[(4 * g + r) * PSTR + l15] = f2b(p0);
      strip[(4 * g + r) * PSTR + 16 + l15] = f2b(p1);
    }
    // wave-private LDS: compiler orders ds_write -> lgkmcnt -> ds_read (alias)
    bf16x8 pa = *reinterpret_cast<const bf16x8*>(&strip[l15 * PSTR + 8 * g]);
#pragma unroll
    for (int n = 0; n < 4; ++n) {
      bf16x8 vb = ld8(vb_b + ((size_t)(n * 16 + l15)) * S + t0 + 8 * g);
      hacc[n] = MFMA(pa, vb, hacc[n]);
    }
  }
#pragma unroll
  for (int n = 0; n < 4; ++n)
#pragma unroll
    for (int r = 0; r < 4; ++r)
      heads[(bh * S + row0 + 4 * g + r) * DK + n * 16 + l15] = hacc[n][r];
}

// ---------------------------------------------------------------------------
// K3: mean over heads + output projection. One block per (b,s) token.
// ---------------------------------------------------------------------------
__global__ __launch_bounds__(256) void out_kernel(
    const float* __restrict__ heads, const float* __restrict__ Wh,
    float* __restrict__ out) {
  const int bs = blockIdx.x;
  const int b = bs >> 11, s = bs & (S - 1);
  const int tid = threadIdx.x;
  __shared__ __align__(16) float pooled[DK];
  if (tid < DK) {
    const float* hb = heads + ((size_t)(b * H) * S + s) * DK + tid;
    float acc = 0.f;
#pragma unroll
    for (int hh = 0; hh < H; ++hh) acc += hb[(size_t)hh * S * DK];
    pooled[tid] = acc * 0.25f;
  }
  __syncthreads();
  const float4* wh4 = (const float4*)(Wh + (size_t)tid * DK);
  const float4* p4 = (const float4*)pooled;
  float4 av = {0.f, 0.f, 0.f, 0.f};
#pragma unroll
  for (int i = 0; i < DK / 4; ++i) {
    float4 w = wh4[i], p = p4[i];
    av.x = fmaf(w.x, p.x, av.x); av.y = fmaf(w.y, p.y, av.y);
    av.z = fmaf(w.z, p.z, av.z); av.w = fmaf(w.w, p.w, av.w);
  }
  out[(size_t)bs * DM + tid] = (av.x + av.y) + (av.z + av.w);
}

extern "C" void kernel_launch(void* const* d_in, const int* in_sizes, int n_in,
                              void* d_out, int out_size, void* d_ws, size_t ws_size,
                              hipStream_t stream) {
  const float* q = (const float*)d_in[0];
  const float* k = (const float*)d_in[1];
  const float* v = (const float*)d_in[2];
  const float* Wq = (const float*)d_in[3];
  const float* Wk = (const float*)d_in[4];
  const float* Wv = (const float*)d_in[5];
  const float* Wh = (const float*)d_in[6];

  float* out = (float*)d_out;                  // [B,S,DM]
  float* attn_out = out + (size_t)B * S * DM;  // [B,S,H,S]

  const size_t n1 = (size_t)B * H * S * DK;  // 2,097,152
  ushort* qhi = (ushort*)d_ws;
  ushort* qlo = qhi + n1;
  ushort* khi = qlo + n1;
  ushort* klo = khi + n1;
  ushort* vT = klo + n1;                      // B*DK*S
  float* heads = (float*)(vT + (size_t)B * DK * S);  // [B,H,S,DK] fp32

  proj_kernel<<<B * S, 256, 0, stream>>>(q, k, v, Wq, Wk, Wv, qhi, qlo, khi, klo, vT);
  attn_kernel<<<(B * H * S / 16) / 4, 256, 0, stream>>>(qhi, qlo, khi, klo, vT, attn_out, heads);
  out_kernel<<<B * S, 256, 0, stream>>>(heads, Wh, out);
}

// Round 3
// 469.577 us; speedup vs baseline: 7.9031x; 1.8690x over previous
//
#include <hip/hip_runtime.h>
#include <hip/hip_bf16.h>
#include <math.h>

#define B 4
#define S 2048
#define H 4
#define DK 64
#define DM 256
#define PSTR 40  // LDS strip stride in bf16 elems: 80B -> conflict-free b128 reads, 16B-aligned

using bf16x8 = __attribute__((ext_vector_type(8))) short;
using f32x4 = __attribute__((ext_vector_type(4))) float;

__device__ inline ushort f2b(float f) {
  __hip_bfloat16 h = __float2bfloat16(f);
  ushort u; __builtin_memcpy(&u, &h, 2); return u;
}
__device__ inline float b2f(ushort u) {
  __hip_bfloat16 h; __builtin_memcpy(&h, &u, 2); return __bfloat162float(h);
}
__device__ inline bf16x8 ld8(const ushort* p) {
  return *reinterpret_cast<const bf16x8*>(p);
}
#define MFMA(a, b, c) __builtin_amdgcn_mfma_f32_16x16x32_bf16((a), (b), (c), 0, 0, 0)

// ---------------------------------------------------------------------------
// K0: split projection weights into bf16 hi/lo (once per call; 576 rows).
// Row-major [out_row][k] so GEMM B-fragments read 16B contiguous per lane.
// ---------------------------------------------------------------------------
__global__ __launch_bounds__(256) void wsplit_kernel(
    const float* __restrict__ Wq, const float* __restrict__ Wk,
    const float* __restrict__ Wv,
    ushort* __restrict__ wqh, ushort* __restrict__ wql,
    ushort* __restrict__ wkh, ushort* __restrict__ wkl,
    ushort* __restrict__ wvh, ushort* __restrict__ wvl) {
  const int row = blockIdx.x;  // 0..575
  const int t = threadIdx.x;   // k
  const float* src; ushort* dh; ushort* dl; int r;
  if (row < 256) { src = Wq; dh = wqh; dl = wql; r = row; }
  else if (row < 512) { src = Wk; dh = wkh; dl = wkl; r = row - 256; }
  else { src = Wv; dh = wvh; dl = wvl; r = row - 512; }
  const float v = src[(size_t)r * DM + t];
  const ushort hi = f2b(v);
  dh[(size_t)r * DM + t] = hi;
  dl[(size_t)r * DM + t] = f2b(v - b2f(hi));
}

// ---------------------------------------------------------------------------
// K1: projection GEMM via MFMA, split-bf16 (3 terms -> near-fp32).
// One wave = 16 token rows x all N outputs. No LDS, no barriers.
// SRC: 0=q -> qhi/qlo, 1=k -> khi/klo, 2=v (N=64) -> vT bf16 [B,DK,S].
// A-frags read fp32 x direct from global (wave consumes full lines),
// converted to hi/lo in registers. B-frags read pre-split W from L2.
// ---------------------------------------------------------------------------
template <int SRC>
__global__ __launch_bounds__(256) void proj_mfma(
    const float* __restrict__ x, const ushort* __restrict__ wh,
    const ushort* __restrict__ wl,
    ushort* __restrict__ ohi, ushort* __restrict__ olo,
    ushort* __restrict__ vT) {
  constexpr int NF = (SRC == 2) ? 4 : 16;
  const int wid = threadIdx.x >> 6;
  const int lane = threadIdx.x & 63;
  const int l15 = lane & 15, g = lane >> 4;
  const int row0 = blockIdx.x * 64 + wid * 16;  // token tile base

  // load & convert A: row = row0 + l15, k = ks*32 + 8g + j
  bf16x8 ah[8], al[8];
  const float* xrow = x + (size_t)(row0 + l15) * DM;
#pragma unroll
  for (int ks = 0; ks < 8; ++ks) {
    float4 f0 = *(const float4*)(xrow + ks * 32 + 8 * g);
    float4 f1 = *(const float4*)(xrow + ks * 32 + 8 * g + 4);
    float fv[8] = {f0.x, f0.y, f0.z, f0.w, f1.x, f1.y, f1.z, f1.w};
    bf16x8 h8, l8;
#pragma unroll
    for (int j = 0; j < 8; ++j) {
      ushort hu = f2b(fv[j]);
      h8[j] = (short)hu;
      l8[j] = (short)f2b(fv[j] - b2f(hu));
    }
    ah[ks] = h8; al[ks] = l8;
  }

  f32x4 acc[NF];
#pragma unroll
  for (int n = 0; n < NF; ++n) acc[n] = (f32x4){0.f, 0.f, 0.f, 0.f};

#pragma unroll
  for (int n = 0; n < NF; ++n) {
    const ushort* wrh = wh + (size_t)(n * 16 + l15) * DM + 8 * g;
    const ushort* wrl = wl + (size_t)(n * 16 + l15) * DM + 8 * g;
#pragma unroll
    for (int ks = 0; ks < 8; ++ks) {
      bf16x8 bh = ld8(wrh + ks * 32);
      bf16x8 bl = ld8(wrl + ks * 32);
      acc[n] = MFMA(ah[ks], bh, acc[n]);
      acc[n] = MFMA(al[ks], bh, acc[n]);
      acc[n] = MFMA(ah[ks], bl, acc[n]);
    }
  }

  // C layout: row = 4*g + r (token), col = n*16 + l15 (output dim)
  if constexpr (SRC != 2) {
#pragma unroll
    for (int n = 0; n < NF; ++n) {
      const int j = n * 16 + l15, h = j >> 6, e = j & 63;
#pragma unroll
      for (int r = 0; r < 4; ++r) {
        const int tok = row0 + 4 * g + r;
        const int b = tok >> 11, s = tok & (S - 1);
        const size_t idx = ((size_t)((b * H + h) * S + s)) * DK + e;
        const float val = acc[n][r];
        const ushort hu = f2b(val);
        ohi[idx] = hu;
        olo[idx] = f2b(val - b2f(hu));
      }
    }
  } else {
#pragma unroll
    for (int n = 0; n < NF; ++n) {
      const int e = n * 16 + l15;
#pragma unroll
      for (int r = 0; r < 4; ++r) {
        const int tok = row0 + 4 * g + r;
        const int b = tok >> 11, s = tok & (S - 1);
        vT[((size_t)b * DK + e) * S + s] = f2b(acc[n][r]);
      }
    }
  }
}

// ---------------------------------------------------------------------------
// K2: attention via MFMA. One wave = 16 query rows of one (b,h).
// Sweep 1: online (max, sumexp) over all 2048 keys (split-bf16 QK^T).
// Sweep 2: recompute scores, normalize, write attn fp32, bounce P through
// wave-private LDS strip to A-fragment layout, accumulate PV (bf16 MFMA, vT).
// ---------------------------------------------------------------------------
#define QK_CHUNK(T0, ACC0, ACC1)                                              \
  do {                                                                        \
    const ushort* kh_ = kbh + ((T0) + l15) * DK + 8 * g;                      \
    const ushort* kl_ = kbl + ((T0) + l15) * DK + 8 * g;                      \
    bf16x8 bh0 = ld8(kh_), bh1 = ld8(kh_ + 32);                               \
    bf16x8 bl0 = ld8(kl_), bl1 = ld8(kl_ + 32);                               \
    bf16x8 ch0 = ld8(kh_ + 16 * DK), ch1 = ld8(kh_ + 16 * DK + 32);           \
    bf16x8 cl0 = ld8(kl_ + 16 * DK), cl1 = ld8(kl_ + 16 * DK + 32);           \
    ACC0 = MFMA(aqh0, bh0, ACC0); ACC0 = MFMA(aqh1, bh1, ACC0);               \
    ACC0 = MFMA(aql0, bh0, ACC0); ACC0 = MFMA(aql1, bh1, ACC0);               \
    ACC0 = MFMA(aqh0, bl0, ACC0); ACC0 = MFMA(aqh1, bl1, ACC0);               \
    ACC1 = MFMA(aqh0, ch0, ACC1); ACC1 = MFMA(aqh1, ch1, ACC1);               \
    ACC1 = MFMA(aql0, ch0, ACC1); ACC1 = MFMA(aql1, ch1, ACC1);               \
    ACC1 = MFMA(aqh0, cl0, ACC1); ACC1 = MFMA(aqh1, cl1, ACC1);               \
  } while (0)

__global__ __launch_bounds__(256) void attn_kernel(
    const ushort* __restrict__ qhi, const ushort* __restrict__ qlo,
    const ushort* __restrict__ khi, const ushort* __restrict__ klo,
    const ushort* __restrict__ vT,
    float* __restrict__ attn_out, float* __restrict__ heads) {
  __shared__ __align__(16) ushort pstrip[4][16 * PSTR];
  const int wid = threadIdx.x >> 6;
  const int lane = threadIdx.x & 63;
  const int l15 = lane & 15, g = lane >> 4;
  const int bid = blockIdx.x;
  // XCD-aware swizzle: grid 512 = 8 XCDs x 64 contiguous blocks
  const int swz = (bid & 7) * 64 + (bid >> 3);
  const int wave = swz * 4 + wid;  // 0..2047
  const int st = wave & 127;
  const int h = (wave >> 7) & 3;
  const int b = wave >> 9;
  const int row0 = st * 16;

  const size_t bh = (size_t)(b * H + h);
  const ushort* qbh = qhi + (bh * S + row0 + l15) * DK;
  const ushort* qbl = qlo + (bh * S + row0 + l15) * DK;
  const bf16x8 aqh0 = ld8(qbh + 8 * g), aqh1 = ld8(qbh + 32 + 8 * g);
  const bf16x8 aql0 = ld8(qbl + 8 * g), aql1 = ld8(qbl + 32 + 8 * g);
  const ushort* kbh = khi + bh * S * DK;
  const ushort* kbl = klo + bh * S * DK;

  // ---- sweep 1: online row max + sumexp ----
  float m4[4] = {-1e30f, -1e30f, -1e30f, -1e30f};
  float s4[4] = {0.f, 0.f, 0.f, 0.f};
#pragma unroll 2
  for (int t0 = 0; t0 < S; t0 += 32) {
    f32x4 acc0 = {0.f, 0.f, 0.f, 0.f}, acc1 = {0.f, 0.f, 0.f, 0.f};
    QK_CHUNK(t0, acc0, acc1);
#pragma unroll
    for (int r = 0; r < 4; ++r) {
      float pm = fmaxf(acc0[r], acc1[r]);
      pm = fmaxf(pm, __shfl_xor(pm, 1));
      pm = fmaxf(pm, __shfl_xor(pm, 2));
      pm = fmaxf(pm, __shfl_xor(pm, 4));
      pm = fmaxf(pm, __shfl_xor(pm, 8));
      float mn = fmaxf(m4[r], pm);
      float es = __expf((acc0[r] - mn) * 0.125f) + __expf((acc1[r] - mn) * 0.125f);
      es += __shfl_xor(es, 1);
      es += __shfl_xor(es, 2);
      es += __shfl_xor(es, 4);
      es += __shfl_xor(es, 8);
      s4[r] = s4[r] * __expf((m4[r] - mn) * 0.125f) + es;
      m4[r] = mn;
    }
  }
  float inv4[4];
#pragma unroll
  for (int r = 0; r < 4; ++r) inv4[r] = 1.f / s4[r];

  // ---- sweep 2: recompute, normalize, write attn, PV ----
  f32x4 hacc[4] = {{0.f, 0.f, 0.f, 0.f}, {0.f, 0.f, 0.f, 0.f},
                   {0.f, 0.f, 0.f, 0.f}, {0.f, 0.f, 0.f, 0.f}};
  const ushort* vb_b = vT + (size_t)b * DK * S;
  float* arows[4];
#pragma unroll
  for (int r = 0; r < 4; ++r)
    arows[r] = attn_out + ((size_t)(b * S + row0 + 4 * g + r) * H + h) * S;
  ushort* strip = pstrip[wid];

#pragma unroll 2
  for (int t0 = 0; t0 < S; t0 += 32) {
    f32x4 acc0 = {0.f, 0.f, 0.f, 0.f}, acc1 = {0.f, 0.f, 0.f, 0.f};
    QK_CHUNK(t0, acc0, acc1);
#pragma unroll
    for (int r = 0; r < 4; ++r) {
      float p0 = __expf((acc0[r] - m4[r]) * 0.125f) * inv4[r];
      float p1 = __expf((acc1[r] - m4[r]) * 0.125f) * inv4[r];
      arows[r][t0 + l15] = p0;
      arows[r][t0 + 16 + l15] = p1;
      strip[(4 * g + r) * PSTR + l15] = f2b(p0);
      strip[(4 * g + r) * PSTR + 16 + l15] = f2b(p1);
    }
    bf16x8 pa = *reinterpret_cast<const bf16x8*>(&strip[l15 * PSTR + 8 * g]);
#pragma unroll
    for (int n = 0; n < 4; ++n) {
      bf16x8 vb = ld8(vb_b + ((size_t)(n * 16 + l15)) * S + t0 + 8 * g);
      hacc[n] = MFMA(pa, vb, hacc[n]);
    }
  }
#pragma unroll
  for (int n = 0; n < 4; ++n)
#pragma unroll
    for (int r = 0; r < 4; ++r)
      heads[(bh * S + row0 + 4 * g + r) * DK + n * 16 + l15] = hacc[n][r];
}

// ---------------------------------------------------------------------------
// K3: mean over heads + output projection. One block per (b,s) token.
// ---------------------------------------------------------------------------
__global__ __launch_bounds__(256) void out_kernel(
    const float* __restrict__ heads, const float* __restrict__ Wh,
    float* __restrict__ out) {
  const int bs = blockIdx.x;
  const int b = bs >> 11, s = bs & (S - 1);
  const int tid = threadIdx.x;
  __shared__ __align__(16) float pooled[DK];
  if (tid < DK) {
    const float* hb = heads + ((size_t)(b * H) * S + s) * DK + tid;
    float acc = 0.f;
#pragma unroll
    for (int hh = 0; hh < H; ++hh) acc += hb[(size_t)hh * S * DK];
    pooled[tid] = acc * 0.25f;
  }
  __syncthreads();
  const float4* wh4 = (const float4*)(Wh + (size_t)tid * DK);
  const float4* p4 = (const float4*)pooled;
  float4 av = {0.f, 0.f, 0.f, 0.f};
#pragma unroll
  for (int i = 0; i < DK / 4; ++i) {
    float4 w = wh4[i], p = p4[i];
    av.x = fmaf(w.x, p.x, av.x); av.y = fmaf(w.y, p.y, av.y);
    av.z = fmaf(w.z, p.z, av.z); av.w = fmaf(w.w, p.w, av.w);
  }
  out[(size_t)bs * DM + tid] = (av.x + av.y) + (av.z + av.w);
}

extern "C" void kernel_launch(void* const* d_in, const int* in_sizes, int n_in,
                              void* d_out, int out_size, void* d_ws, size_t ws_size,
                              hipStream_t stream) {
  const float* q = (const float*)d_in[0];
  const float* k = (const float*)d_in[1];
  const float* v = (const float*)d_in[2];
  const float* Wq = (const float*)d_in[3];
  const float* Wk = (const float*)d_in[4];
  const float* Wv = (const float*)d_in[5];
  const float* Wh = (const float*)d_in[6];

  float* out = (float*)d_out;                  // [B,S,DM]
  float* attn_out = out + (size_t)B * S * DM;  // [B,S,H,S]

  const size_t n1 = (size_t)B * H * S * DK;  // 2,097,152
  ushort* qhi = (ushort*)d_ws;
  ushort* qlo = qhi + n1;
  ushort* khi = qlo + n1;
  ushort* klo = khi + n1;
  ushort* vT = klo + n1;                              // B*DK*S
  float* heads = (float*)(vT + (size_t)B * DK * S);   // [B,H,S,DK] fp32
  ushort* wqh = (ushort*)(heads + n1);                // 65536 each
  ushort* wql = wqh + (size_t)H * DK * DM;
  ushort* wkh = wql + (size_t)H * DK * DM;
  ushort* wkl = wkh + (size_t)H * DK * DM;
  ushort* wvh = wkl + (size_t)H * DK * DM;            // 16384 each
  ushort* wvl = wvh + (size_t)DK * DM;

  wsplit_kernel<<<576, 256, 0, stream>>>(Wq, Wk, Wv, wqh, wql, wkh, wkl, wvh, wvl);
  proj_mfma<0><<<B * S / 64, 256, 0, stream>>>(q, wqh, wql, qhi, qlo, nullptr);
  proj_mfma<1><<<B * S / 64, 256, 0, stream>>>(k, wkh, wkl, khi, klo, nullptr);
  proj_mfma<2><<<B * S / 64, 256, 0, stream>>>(v, wvh, wvl, nullptr, nullptr, vT);
  attn_kernel<<<B * H * S / 64, 256, 0, stream>>>(qhi, qlo, khi, klo, vT, attn_out, heads);
  out_kernel<<<B * S, 256, 0, stream>>>(heads, Wh, out);
}

// Round 4
// 467.596 us; speedup vs baseline: 7.9366x; 1.0042x over previous
//
#include <hip/hip_runtime.h>
#include <hip/hip_bf16.h>
#include <math.h>

#define B 4
#define S 2048
#define H 4
#define DK 64
#define DM 256

using bf16x8 = __attribute__((ext_vector_type(8))) short;
using bf16x4 = __attribute__((ext_vector_type(4))) short;
using f32x4 = __attribute__((ext_vector_type(4))) float;

__device__ inline ushort f2b(float f) {
  __hip_bfloat16 h = __float2bfloat16(f);
  ushort u; __builtin_memcpy(&u, &h, 2); return u;
}
__device__ inline float b2f(ushort u) {
  __hip_bfloat16 h; __builtin_memcpy(&h, &u, 2); return __bfloat162float(h);
}
__device__ inline bf16x8 ld8(const ushort* p) {
  return *reinterpret_cast<const bf16x8*>(p);
}
__device__ inline bf16x4 ld4(const ushort* p) {
  return *reinterpret_cast<const bf16x4*>(p);
}
#define MFMA(a, b, c) __builtin_amdgcn_mfma_f32_16x16x32_bf16((a), (b), (c), 0, 0, 0)

#if __has_builtin(__builtin_amdgcn_mfma_f32_16x16x16bf16_1k)
__device__ inline f32x4 MFMA16(bf16x4 a, bf16x4 b, f32x4 c) {
  return __builtin_amdgcn_mfma_f32_16x16x16bf16_1k(a, b, c, 0, 0, 0);
}
#else
__device__ inline f32x4 MFMA16(bf16x4 a, bf16x4 b, f32x4 c) {
  asm("v_mfma_f32_16x16x16_bf16 %0, %1, %2, %0" : "+v"(c) : "v"(a), "v"(b));
  return c;
}
#endif

// ---------------------------------------------------------------------------
// K0: split projection weights into bf16 hi/lo (once per call; 576 rows).
// ---------------------------------------------------------------------------
__global__ __launch_bounds__(256) void wsplit_kernel(
    const float* __restrict__ Wq, const float* __restrict__ Wk,
    const float* __restrict__ Wv,
    ushort* __restrict__ wqh, ushort* __restrict__ wql,
    ushort* __restrict__ wkh, ushort* __restrict__ wkl,
    ushort* __restrict__ wvh, ushort* __restrict__ wvl) {
  const int row = blockIdx.x;  // 0..575
  const int t = threadIdx.x;   // k
  const float* src; ushort* dh; ushort* dl; int r;
  if (row < 256) { src = Wq; dh = wqh; dl = wql; r = row; }
  else if (row < 512) { src = Wk; dh = wkh; dl = wkl; r = row - 256; }
  else { src = Wv; dh = wvh; dl = wvl; r = row - 512; }
  const float v = src[(size_t)r * DM + t];
  const ushort hi = f2b(v);
  dh[(size_t)r * DM + t] = hi;
  dl[(size_t)r * DM + t] = f2b(v - b2f(hi));
}

// ---------------------------------------------------------------------------
// K1: projection GEMM via MFMA, split-bf16 (3 terms -> near-fp32).
// ---------------------------------------------------------------------------
template <int SRC>
__global__ __launch_bounds__(256) void proj_mfma(
    const float* __restrict__ x, const ushort* __restrict__ wh,
    const ushort* __restrict__ wl,
    ushort* __restrict__ ohi, ushort* __restrict__ olo,
    ushort* __restrict__ vT) {
  constexpr int NF = (SRC == 2) ? 4 : 16;
  const int wid = threadIdx.x >> 6;
  const int lane = threadIdx.x & 63;
  const int l15 = lane & 15, g = lane >> 4;
  const int row0 = blockIdx.x * 64 + wid * 16;

  bf16x8 ah[8], al[8];
  const float* xrow = x + (size_t)(row0 + l15) * DM;
#pragma unroll
  for (int ks = 0; ks < 8; ++ks) {
    float4 f0 = *(const float4*)(xrow + ks * 32 + 8 * g);
    float4 f1 = *(const float4*)(xrow + ks * 32 + 8 * g + 4);
    float fv[8] = {f0.x, f0.y, f0.z, f0.w, f1.x, f1.y, f1.z, f1.w};
    bf16x8 h8, l8;
#pragma unroll
    for (int j = 0; j < 8; ++j) {
      ushort hu = f2b(fv[j]);
      h8[j] = (short)hu;
      l8[j] = (short)f2b(fv[j] - b2f(hu));
    }
    ah[ks] = h8; al[ks] = l8;
  }

  f32x4 acc[NF];
#pragma unroll
  for (int n = 0; n < NF; ++n) acc[n] = (f32x4){0.f, 0.f, 0.f, 0.f};

#pragma unroll
  for (int n = 0; n < NF; ++n) {
    const ushort* wrh = wh + (size_t)(n * 16 + l15) * DM + 8 * g;
    const ushort* wrl = wl + (size_t)(n * 16 + l15) * DM + 8 * g;
#pragma unroll
    for (int ks = 0; ks < 8; ++ks) {
      bf16x8 bh = ld8(wrh + ks * 32);
      bf16x8 bl = ld8(wrl + ks * 32);
      acc[n] = MFMA(ah[ks], bh, acc[n]);
      acc[n] = MFMA(al[ks], bh, acc[n]);
      acc[n] = MFMA(ah[ks], bl, acc[n]);
    }
  }

  if constexpr (SRC != 2) {
#pragma unroll
    for (int n = 0; n < NF; ++n) {
      const int j = n * 16 + l15, h = j >> 6, e = j & 63;
#pragma unroll
      for (int r = 0; r < 4; ++r) {
        const int tok = row0 + 4 * g + r;
        const int b = tok >> 11, s = tok & (S - 1);
        const size_t idx = ((size_t)((b * H + h) * S + s)) * DK + e;
        const float val = acc[n][r];
        const ushort hu = f2b(val);
        ohi[idx] = hu;
        olo[idx] = f2b(val - b2f(hu));
      }
    }
  } else {
#pragma unroll
    for (int n = 0; n < NF; ++n) {
      const int e = n * 16 + l15;
#pragma unroll
      for (int r = 0; r < 4; ++r) {
        const int tok = row0 + 4 * g + r;
        const int b = tok >> 11, s = tok & (S - 1);
        vT[((size_t)b * DK + e) * S + s] = f2b(acc[n][r]);
      }
    }
  }
}

// ---------------------------------------------------------------------------
// K2: attention via swapped MFMA (S^T = K.Q^T): each lane owns ONE query row
// (q = l15) and keys 4g+r -> softmax is per-lane, attn writes are float4,
// and P feeds PV directly as the A-operand of 16x16x16 MFMA. No LDS, no
// barriers, no max-shift (scores*0.125 bounded ~10 -> fp32-safe sums).
// Sweep 1 (sum): hi*hi only. Sweep 2 (attn+PV): full 3-term split.
// ---------------------------------------------------------------------------
__global__ __launch_bounds__(256) void attn_kernel(
    const ushort* __restrict__ qhi, const ushort* __restrict__ qlo,
    const ushort* __restrict__ khi, const ushort* __restrict__ klo,
    const ushort* __restrict__ vT,
    float* __restrict__ attn_out, float* __restrict__ heads) {
  const int wid = threadIdx.x >> 6;
  const int lane = threadIdx.x & 63;
  const int l15 = lane & 15, g = lane >> 4;
  const int bid = blockIdx.x;
  // XCD-aware swizzle: grid 512 = 8 XCDs x 64 contiguous blocks
  const int swz = (bid & 7) * 64 + (bid >> 3);
  const int wave = swz * 4 + wid;  // 0..2047
  const int st = wave & 127;
  const int h = (wave >> 7) & 3;
  const int b = wave >> 9;
  const int row0 = st * 16;
  const float SC = 0.125f;  // 1/sqrt(64)

  const size_t bh = (size_t)(b * H + h);
  // Q fragments (B-operand of swapped QK): Q[row0+l15][k]
  const ushort* qbh = qhi + (bh * S + row0 + l15) * DK;
  const ushort* qbl = qlo + (bh * S + row0 + l15) * DK;
  const bf16x8 aqh0 = ld8(qbh + 8 * g), aqh1 = ld8(qbh + 32 + 8 * g);
  const bf16x8 aql0 = ld8(qbl + 8 * g), aql1 = ld8(qbl + 32 + 8 * g);
  const ushort* kbh = khi + bh * S * DK;
  const ushort* kbl = klo + bh * S * DK;

  // ---- sweep 1: per-lane sum of exp(score*SC), hi*hi scores ----
  float ssum = 0.f;
#pragma unroll 2
  for (int t0 = 0; t0 < S; t0 += 32) {
    const ushort* kh_ = kbh + (size_t)(t0 + l15) * DK + 8 * g;
    bf16x8 bh0 = ld8(kh_), bh1 = ld8(kh_ + 32);
    bf16x8 ch0 = ld8(kh_ + 16 * DK), ch1 = ld8(kh_ + 16 * DK + 32);
    f32x4 acc0 = {0.f, 0.f, 0.f, 0.f}, acc1 = {0.f, 0.f, 0.f, 0.f};
    acc0 = MFMA(bh0, aqh0, acc0); acc0 = MFMA(bh1, aqh1, acc0);
    acc1 = MFMA(ch0, aqh0, acc1); acc1 = MFMA(ch1, aqh1, acc1);
    float e0 = __expf(acc0[0] * SC) + __expf(acc0[1] * SC);
    float e1 = __expf(acc0[2] * SC) + __expf(acc0[3] * SC);
    float e2 = __expf(acc1[0] * SC) + __expf(acc1[1] * SC);
    float e3 = __expf(acc1[2] * SC) + __expf(acc1[3] * SC);
    ssum += (e0 + e1) + (e2 + e3);
  }
  // combine across the 4 g-lanes holding the same query row
  ssum += __shfl_xor(ssum, 16, 64);
  ssum += __shfl_xor(ssum, 32, 64);
  const float inv = 1.f / ssum;

  // ---- sweep 2: full-precision scores, normalize, write attn, PV ----
  f32x4 hacc[4] = {{0.f, 0.f, 0.f, 0.f}, {0.f, 0.f, 0.f, 0.f},
                   {0.f, 0.f, 0.f, 0.f}, {0.f, 0.f, 0.f, 0.f}};
  const ushort* vb_b = vT + (size_t)b * DK * S;
  float* arow = attn_out + (((size_t)(b * S + row0 + l15)) * H + h) * S;

  for (int t0 = 0; t0 < S; t0 += 32) {
    const ushort* kh_ = kbh + (size_t)(t0 + l15) * DK + 8 * g;
    const ushort* kl_ = kbl + (size_t)(t0 + l15) * DK + 8 * g;
    bf16x8 bh0 = ld8(kh_), bh1 = ld8(kh_ + 32);
    bf16x8 bl0 = ld8(kl_), bl1 = ld8(kl_ + 32);
    bf16x8 ch0 = ld8(kh_ + 16 * DK), ch1 = ld8(kh_ + 16 * DK + 32);
    bf16x8 cl0 = ld8(kl_ + 16 * DK), cl1 = ld8(kl_ + 16 * DK + 32);
    f32x4 acc0 = {0.f, 0.f, 0.f, 0.f}, acc1 = {0.f, 0.f, 0.f, 0.f};
    acc0 = MFMA(bh0, aqh0, acc0); acc0 = MFMA(bh1, aqh1, acc0);
    acc0 = MFMA(bl0, aqh0, acc0); acc0 = MFMA(bl1, aqh1, acc0);
    acc0 = MFMA(bh0, aql0, acc0); acc0 = MFMA(bh1, aql1, acc0);
    acc1 = MFMA(ch0, aqh0, acc1); acc1 = MFMA(ch1, aqh1, acc1);
    acc1 = MFMA(cl0, aqh0, acc1); acc1 = MFMA(cl1, aqh1, acc1);
    acc1 = MFMA(ch0, aql0, acc1); acc1 = MFMA(ch1, aql1, acc1);

    float p0 = __expf(acc0[0] * SC) * inv;
    float p1 = __expf(acc0[1] * SC) * inv;
    float p2 = __expf(acc0[2] * SC) * inv;
    float p3 = __expf(acc0[3] * SC) * inv;
    float p4 = __expf(acc1[0] * SC) * inv;
    float p5 = __expf(acc1[1] * SC) * inv;
    float p6 = __expf(acc1[2] * SC) * inv;
    float p7 = __expf(acc1[3] * SC) * inv;

    // float4 attn writes: keys t0+4g.. and t0+16+4g.. of row q=row0+l15
    *(float4*)(arow + t0 + 4 * g) = (float4){p0, p1, p2, p3};
    *(float4*)(arow + t0 + 16 + 4 * g) = (float4){p4, p5, p6, p7};

    // P as A-fragment of 16x16x16 MFMA: A[l15][4g+j] = P[q=l15][key]
    bf16x4 pa0, pa1;
    pa0[0] = (short)f2b(p0); pa0[1] = (short)f2b(p1);
    pa0[2] = (short)f2b(p2); pa0[3] = (short)f2b(p3);
    pa1[0] = (short)f2b(p4); pa1[1] = (short)f2b(p5);
    pa1[2] = (short)f2b(p6); pa1[3] = (short)f2b(p7);
#pragma unroll
    for (int n = 0; n < 4; ++n) {
      bf16x4 vb0 = ld4(vb_b + (size_t)(n * 16 + l15) * S + t0 + 4 * g);
      bf16x4 vb1 = ld4(vb_b + (size_t)(n * 16 + l15) * S + t0 + 16 + 4 * g);
      hacc[n] = MFMA16(pa0, vb0, hacc[n]);
      hacc[n] = MFMA16(pa1, vb1, hacc[n]);
    }
  }
#pragma unroll
  for (int n = 0; n < 4; ++n)
#pragma unroll
    for (int r = 0; r < 4; ++r)
      heads[(bh * S + row0 + 4 * g + r) * DK + n * 16 + l15] = hacc[n][r];
}

// ---------------------------------------------------------------------------
// K3: mean over heads + output projection. One block per (b,s) token.
// ---------------------------------------------------------------------------
__global__ __launch_bounds__(256) void out_kernel(
    const float* __restrict__ heads, const float* __restrict__ Wh,
    float* __restrict__ out) {
  const int bs = blockIdx.x;
  const int b = bs >> 11, s = bs & (S - 1);
  const int tid = threadIdx.x;
  __shared__ __align__(16) float pooled[DK];
  if (tid < DK) {
    const float* hb = heads + ((size_t)(b * H) * S + s) * DK + tid;
    float acc = 0.f;
#pragma unroll
    for (int hh = 0; hh < H; ++hh) acc += hb[(size_t)hh * S * DK];
    pooled[tid] = acc * 0.25f;
  }
  __syncthreads();
  const float4* wh4 = (const float4*)(Wh + (size_t)tid * DK);
  const float4* p4 = (const float4*)pooled;
  float4 av = {0.f, 0.f, 0.f, 0.f};
#pragma unroll
  for (int i = 0; i < DK / 4; ++i) {
    float4 w = wh4[i], p = p4[i];
    av.x = fmaf(w.x, p.x, av.x); av.y = fmaf(w.y, p.y, av.y);
    av.z = fmaf(w.z, p.z, av.z); av.w = fmaf(w.w, p.w, av.w);
  }
  out[(size_t)bs * DM + tid] = (av.x + av.y) + (av.z + av.w);
}

extern "C" void kernel_launch(void* const* d_in, const int* in_sizes, int n_in,
                              void* d_out, int out_size, void* d_ws, size_t ws_size,
                              hipStream_t stream) {
  const float* q = (const float*)d_in[0];
  const float* k = (const float*)d_in[1];
  const float* v = (const float*)d_in[2];
  const float* Wq = (const float*)d_in[3];
  const float* Wk = (const float*)d_in[4];
  const float* Wv = (const float*)d_in[5];
  const float* Wh = (const float*)d_in[6];

  float* out = (float*)d_out;                  // [B,S,DM]
  float* attn_out = out + (size_t)B * S * DM;  // [B,S,H,S]

  const size_t n1 = (size_t)B * H * S * DK;  // 2,097,152
  ushort* qhi = (ushort*)d_ws;
  ushort* qlo = qhi + n1;
  ushort* khi = qlo + n1;
  ushort* klo = khi + n1;
  ushort* vT = klo + n1;                              // B*DK*S
  float* heads = (float*)(vT + (size_t)B * DK * S);   // [B,H,S,DK] fp32
  ushort* wqh = (ushort*)(heads + n1);                // 65536 each
  ushort* wql = wqh + (size_t)H * DK * DM;
  ushort* wkh = wql + (size_t)H * DK * DM;
  ushort* wkl = wkh + (size_t)H * DK * DM;
  ushort* wvh = wkl + (size_t)H * DK * DM;            // 16384 each
  ushort* wvl = wvh + (size_t)DK * DM;

  wsplit_kernel<<<576, 256, 0, stream>>>(Wq, Wk, Wv, wqh, wql, wkh, wkl, wvh, wvl);
  proj_mfma<0><<<B * S / 64, 256, 0, stream>>>(q, wqh, wql, qhi, qlo, nullptr);
  proj_mfma<1><<<B * S / 64, 256, 0, stream>>>(k, wkh, wkl, khi, klo, nullptr);
  proj_mfma<2><<<B * S / 64, 256, 0, stream>>>(v, wvh, wvl, nullptr, nullptr, vT);
  attn_kernel<<<B * H * S / 64, 256, 0, stream>>>(qhi, qlo, khi, klo, vT, attn_out, heads);
  out_kernel<<<B * S, 256, 0, stream>>>(heads, Wh, out);
}

// Round 5
// 423.646 us; speedup vs baseline: 8.7600x; 1.1037x over previous
//
#include <hip/hip_runtime.h>
#include <hip/hip_bf16.h>
#include <math.h>

#define B 4
#define S 2048
#define H 4
#define DK 64
#define DM 256

using bf16x8 = __attribute__((ext_vector_type(8))) short;
using bf16x4 = __attribute__((ext_vector_type(4))) short;
using f32x4 = __attribute__((ext_vector_type(4))) float;

__device__ inline ushort f2b(float f) {
  __hip_bfloat16 h = __float2bfloat16(f);
  ushort u; __builtin_memcpy(&u, &h, 2); return u;
}
__device__ inline float b2f(ushort u) {
  __hip_bfloat16 h; __builtin_memcpy(&h, &u, 2); return __bfloat162float(h);
}
__device__ inline bf16x8 ld8(const ushort* p) {
  return *reinterpret_cast<const bf16x8*>(p);
}
__device__ inline bf16x4 ld4(const ushort* p) {
  return *reinterpret_cast<const bf16x4*>(p);
}
#define MFMA(a, b, c) __builtin_amdgcn_mfma_f32_16x16x32_bf16((a), (b), (c), 0, 0, 0)

#if __has_builtin(__builtin_amdgcn_mfma_f32_16x16x16bf16_1k)
__device__ inline f32x4 MFMA16(bf16x4 a, bf16x4 b, f32x4 c) {
  return __builtin_amdgcn_mfma_f32_16x16x16bf16_1k(a, b, c, 0, 0, 0);
}
#else
__device__ inline f32x4 MFMA16(bf16x4 a, bf16x4 b, f32x4 c) {
  asm("v_mfma_f32_16x16x16_bf16 %0, %1, %2, %0" : "+v"(c) : "v"(a), "v"(b));
  return c;
}
#endif

// ---------------------------------------------------------------------------
// K0: split projection weights into bf16 hi/lo (once per call; 576 rows).
// ---------------------------------------------------------------------------
__global__ __launch_bounds__(256) void wsplit_kernel(
    const float* __restrict__ Wq, const float* __restrict__ Wk,
    const float* __restrict__ Wv,
    ushort* __restrict__ wqh, ushort* __restrict__ wql,
    ushort* __restrict__ wkh, ushort* __restrict__ wkl,
    ushort* __restrict__ wvh, ushort* __restrict__ wvl) {
  const int row = blockIdx.x;  // 0..575
  const int t = threadIdx.x;   // k
  const float* src; ushort* dh; ushort* dl; int r;
  if (row < 256) { src = Wq; dh = wqh; dl = wql; r = row; }
  else if (row < 512) { src = Wk; dh = wkh; dl = wkl; r = row - 256; }
  else { src = Wv; dh = wvh; dl = wvl; r = row - 512; }
  const float v = src[(size_t)r * DM + t];
  const ushort hi = f2b(v);
  dh[(size_t)r * DM + t] = hi;
  dl[(size_t)r * DM + t] = f2b(v - b2f(hi));
}

// ---------------------------------------------------------------------------
// K1a: q/k projection GEMM, split-bf16. Grid = head*128 + tile (512 blocks):
// each block = 64 token rows x one head's 64 output dims (NF=4).
// ---------------------------------------------------------------------------
template <int SRC>  // 0=q, 1=k
__global__ __launch_bounds__(256) void proj_qk(
    const float* __restrict__ x, const ushort* __restrict__ wh,
    const ushort* __restrict__ wl,
    ushort* __restrict__ ohi, ushort* __restrict__ olo) {
  const int tile = blockIdx.x & 127;
  const int h = blockIdx.x >> 7;
  const int wid = threadIdx.x >> 6;
  const int lane = threadIdx.x & 63;
  const int l15 = lane & 15, g = lane >> 4;
  const int row0 = tile * 64 + wid * 16;

  bf16x8 ah[8], al[8];
  const float* xrow = x + (size_t)(row0 + l15) * DM;
#pragma unroll
  for (int ks = 0; ks < 8; ++ks) {
    float4 f0 = *(const float4*)(xrow + ks * 32 + 8 * g);
    float4 f1 = *(const float4*)(xrow + ks * 32 + 8 * g + 4);
    float fv[8] = {f0.x, f0.y, f0.z, f0.w, f1.x, f1.y, f1.z, f1.w};
    bf16x8 h8, l8;
#pragma unroll
    for (int j = 0; j < 8; ++j) {
      ushort hu = f2b(fv[j]);
      h8[j] = (short)hu;
      l8[j] = (short)f2b(fv[j] - b2f(hu));
    }
    ah[ks] = h8; al[ks] = l8;
  }

  f32x4 acc[4];
#pragma unroll
  for (int n = 0; n < 4; ++n) acc[n] = (f32x4){0.f, 0.f, 0.f, 0.f};

#pragma unroll
  for (int n = 0; n < 4; ++n) {
    const ushort* wrh = wh + (size_t)(h * DK + n * 16 + l15) * DM + 8 * g;
    const ushort* wrl = wl + (size_t)(h * DK + n * 16 + l15) * DM + 8 * g;
#pragma unroll
    for (int ks = 0; ks < 8; ++ks) {
      bf16x8 bh = ld8(wrh + ks * 32);
      bf16x8 bl = ld8(wrl + ks * 32);
      acc[n] = MFMA(ah[ks], bh, acc[n]);
      acc[n] = MFMA(al[ks], bh, acc[n]);
      acc[n] = MFMA(ah[ks], bl, acc[n]);
    }
  }

#pragma unroll
  for (int n = 0; n < 4; ++n) {
    const int e = n * 16 + l15;
#pragma unroll
    for (int r = 0; r < 4; ++r) {
      const int tok = row0 + 4 * g + r;
      const int b = tok >> 11, s = tok & (S - 1);
      const size_t idx = ((size_t)((b * H + h) * S + s)) * DK + e;
      const float val = acc[n][r];
      const ushort hu = f2b(val);
      ohi[idx] = hu;
      olo[idx] = f2b(val - b2f(hu));
    }
  }
}

// ---------------------------------------------------------------------------
// K1b: v projection GEMM (shared across heads), NF=4, grid 128.
// ---------------------------------------------------------------------------
__global__ __launch_bounds__(256) void proj_v(
    const float* __restrict__ x, const ushort* __restrict__ wh,
    const ushort* __restrict__ wl, ushort* __restrict__ vT) {
  const int wid = threadIdx.x >> 6;
  const int lane = threadIdx.x & 63;
  const int l15 = lane & 15, g = lane >> 4;
  const int row0 = blockIdx.x * 64 + wid * 16;

  bf16x8 ah[8], al[8];
  const float* xrow = x + (size_t)(row0 + l15) * DM;
#pragma unroll
  for (int ks = 0; ks < 8; ++ks) {
    float4 f0 = *(const float4*)(xrow + ks * 32 + 8 * g);
    float4 f1 = *(const float4*)(xrow + ks * 32 + 8 * g + 4);
    float fv[8] = {f0.x, f0.y, f0.z, f0.w, f1.x, f1.y, f1.z, f1.w};
    bf16x8 h8, l8;
#pragma unroll
    for (int j = 0; j < 8; ++j) {
      ushort hu = f2b(fv[j]);
      h8[j] = (short)hu;
      l8[j] = (short)f2b(fv[j] - b2f(hu));
    }
    ah[ks] = h8; al[ks] = l8;
  }

  f32x4 acc[4];
#pragma unroll
  for (int n = 0; n < 4; ++n) acc[n] = (f32x4){0.f, 0.f, 0.f, 0.f};
#pragma unroll
  for (int n = 0; n < 4; ++n) {
    const ushort* wrh = wh + (size_t)(n * 16 + l15) * DM + 8 * g;
    const ushort* wrl = wl + (size_t)(n * 16 + l15) * DM + 8 * g;
#pragma unroll
    for (int ks = 0; ks < 8; ++ks) {
      bf16x8 bh = ld8(wrh + ks * 32);
      bf16x8 bl = ld8(wrl + ks * 32);
      acc[n] = MFMA(ah[ks], bh, acc[n]);
      acc[n] = MFMA(al[ks], bh, acc[n]);
      acc[n] = MFMA(ah[ks], bl, acc[n]);
    }
  }
#pragma unroll
  for (int n = 0; n < 4; ++n) {
    const int e = n * 16 + l15;
#pragma unroll
    for (int r = 0; r < 4; ++r) {
      const int tok = row0 + 4 * g + r;
      const int b = tok >> 11, s = tok & (S - 1);
      vT[((size_t)b * DK + e) * S + s] = f2b(acc[n][r]);
    }
  }
}

// ---------------------------------------------------------------------------
// K2: attention, swapped MFMA, KEY-SPLIT across the block's 4 waves.
// Block = one 16-row tile of one (b,h); wave w owns keys [512w, 512w+512).
// Sweep 1: per-wave partial sumexp (hi*hi) -> LDS combine (1 barrier).
// Sweep 2: 3-term scores, normalize, float4 attn writes, per-wave partial PV
// -> LDS combine (1 barrier) -> coalesced heads write.
// Grid 2048 blocks -> 8 waves/SIMD (latency hiding).
// ---------------------------------------------------------------------------
__global__ __launch_bounds__(256) void attn_kernel(
    const ushort* __restrict__ qhi, const ushort* __restrict__ qlo,
    const ushort* __restrict__ khi, const ushort* __restrict__ klo,
    const ushort* __restrict__ vT,
    float* __restrict__ attn_out, float* __restrict__ heads) {
  __shared__ float ssum_sh[4][16];
  __shared__ __align__(16) float hpart[4][16][DK];  // 16 KB
  const int wid = threadIdx.x >> 6;
  const int lane = threadIdx.x & 63;
  const int l15 = lane & 15, g = lane >> 4;
  const int tid = threadIdx.x;
  const int bid = blockIdx.x;
  // XCD swizzle: 2048 blocks, XCD x gets swz range [x*256, x*256+256)
  const int swz = (bid & 7) * 256 + (bid >> 3);
  const int st = swz & 127;
  const int h = (swz >> 7) & 3;
  const int b = swz >> 9;
  const int row0 = st * 16;
  const float SC = 0.125f;  // 1/sqrt(64)
  const int t_lo = wid * (S / 4), t_hi = t_lo + (S / 4);

  const size_t bh = (size_t)(b * H + h);
  const ushort* qbh = qhi + (bh * S + row0 + l15) * DK;
  const ushort* qbl = qlo + (bh * S + row0 + l15) * DK;
  const bf16x8 aqh0 = ld8(qbh + 8 * g), aqh1 = ld8(qbh + 32 + 8 * g);
  const bf16x8 aql0 = ld8(qbl + 8 * g), aql1 = ld8(qbl + 32 + 8 * g);
  const ushort* kbh = khi + bh * S * DK;
  const ushort* kbl = klo + bh * S * DK;

  // ---- sweep 1: per-lane partial sum of exp(score*SC), hi*hi scores ----
  float ssum = 0.f;
#pragma unroll 2
  for (int t0 = t_lo; t0 < t_hi; t0 += 32) {
    const ushort* kh_ = kbh + (size_t)(t0 + l15) * DK + 8 * g;
    bf16x8 bh0 = ld8(kh_), bh1 = ld8(kh_ + 32);
    bf16x8 ch0 = ld8(kh_ + 16 * DK), ch1 = ld8(kh_ + 16 * DK + 32);
    f32x4 acc0 = {0.f, 0.f, 0.f, 0.f}, acc1 = {0.f, 0.f, 0.f, 0.f};
    acc0 = MFMA(bh0, aqh0, acc0); acc0 = MFMA(bh1, aqh1, acc0);
    acc1 = MFMA(ch0, aqh0, acc1); acc1 = MFMA(ch1, aqh1, acc1);
    float e0 = __expf(acc0[0] * SC) + __expf(acc0[1] * SC);
    float e1 = __expf(acc0[2] * SC) + __expf(acc0[3] * SC);
    float e2 = __expf(acc1[0] * SC) + __expf(acc1[1] * SC);
    float e3 = __expf(acc1[2] * SC) + __expf(acc1[3] * SC);
    ssum += (e0 + e1) + (e2 + e3);
  }
  ssum += __shfl_xor(ssum, 16, 64);
  ssum += __shfl_xor(ssum, 32, 64);
  if (g == 0) ssum_sh[wid][l15] = ssum;
  __syncthreads();
  const float inv =
      1.f / (ssum_sh[0][l15] + ssum_sh[1][l15] + ssum_sh[2][l15] + ssum_sh[3][l15]);

  // ---- sweep 2: full-precision scores, normalize, write attn, partial PV ----
  f32x4 hacc[4] = {{0.f, 0.f, 0.f, 0.f}, {0.f, 0.f, 0.f, 0.f},
                   {0.f, 0.f, 0.f, 0.f}, {0.f, 0.f, 0.f, 0.f}};
  const ushort* vb_b = vT + (size_t)b * DK * S;
  float* arow = attn_out + (((size_t)(b * S + row0 + l15)) * H + h) * S;

#pragma unroll 2
  for (int t0 = t_lo; t0 < t_hi; t0 += 32) {
    const ushort* kh_ = kbh + (size_t)(t0 + l15) * DK + 8 * g;
    const ushort* kl_ = kbl + (size_t)(t0 + l15) * DK + 8 * g;
    bf16x8 bh0 = ld8(kh_), bh1 = ld8(kh_ + 32);
    bf16x8 bl0 = ld8(kl_), bl1 = ld8(kl_ + 32);
    bf16x8 ch0 = ld8(kh_ + 16 * DK), ch1 = ld8(kh_ + 16 * DK + 32);
    bf16x8 cl0 = ld8(kl_ + 16 * DK), cl1 = ld8(kl_ + 16 * DK + 32);
    f32x4 acc0 = {0.f, 0.f, 0.f, 0.f}, acc1 = {0.f, 0.f, 0.f, 0.f};
    acc0 = MFMA(bh0, aqh0, acc0); acc0 = MFMA(bh1, aqh1, acc0);
    acc0 = MFMA(bl0, aqh0, acc0); acc0 = MFMA(bl1, aqh1, acc0);
    acc0 = MFMA(bh0, aql0, acc0); acc0 = MFMA(bh1, aql1, acc0);
    acc1 = MFMA(ch0, aqh0, acc1); acc1 = MFMA(ch1, aqh1, acc1);
    acc1 = MFMA(cl0, aqh0, acc1); acc1 = MFMA(cl1, aqh1, acc1);
    acc1 = MFMA(ch0, aql0, acc1); acc1 = MFMA(ch1, aql1, acc1);

    float p0 = __expf(acc0[0] * SC) * inv;
    float p1 = __expf(acc0[1] * SC) * inv;
    float p2 = __expf(acc0[2] * SC) * inv;
    float p3 = __expf(acc0[3] * SC) * inv;
    float p4 = __expf(acc1[0] * SC) * inv;
    float p5 = __expf(acc1[1] * SC) * inv;
    float p6 = __expf(acc1[2] * SC) * inv;
    float p7 = __expf(acc1[3] * SC) * inv;

    *(float4*)(arow + t0 + 4 * g) = (float4){p0, p1, p2, p3};
    *(float4*)(arow + t0 + 16 + 4 * g) = (float4){p4, p5, p6, p7};

    bf16x4 pa0, pa1;
    pa0[0] = (short)f2b(p0); pa0[1] = (short)f2b(p1);
    pa0[2] = (short)f2b(p2); pa0[3] = (short)f2b(p3);
    pa1[0] = (short)f2b(p4); pa1[1] = (short)f2b(p5);
    pa1[2] = (short)f2b(p6); pa1[3] = (short)f2b(p7);
#pragma unroll
    for (int n = 0; n < 4; ++n) {
      bf16x4 vb0 = ld4(vb_b + (size_t)(n * 16 + l15) * S + t0 + 4 * g);
      bf16x4 vb1 = ld4(vb_b + (size_t)(n * 16 + l15) * S + t0 + 16 + 4 * g);
      hacc[n] = MFMA16(pa0, vb0, hacc[n]);
      hacc[n] = MFMA16(pa1, vb1, hacc[n]);
    }
  }

  // combine partial PV across waves via LDS
#pragma unroll
  for (int n = 0; n < 4; ++n)
#pragma unroll
    for (int r = 0; r < 4; ++r)
      hpart[wid][4 * g + r][n * 16 + l15] = hacc[n][r];
  __syncthreads();
#pragma unroll
  for (int i = 0; i < 4; ++i) {
    const int e = tid + i * 256;     // 0..1023
    const int row = e >> 6, dim = e & 63;
    const float sum = hpart[0][row][dim] + hpart[1][row][dim] +
                      hpart[2][row][dim] + hpart[3][row][dim];
    heads[(bh * S + row0 + row) * DK + dim] = sum;
  }
}

// ---------------------------------------------------------------------------
// K3: mean over heads + output projection. One block per (b,s) token.
// ---------------------------------------------------------------------------
__global__ __launch_bounds__(256) void out_kernel(
    const float* __restrict__ heads, const float* __restrict__ Wh,
    float* __restrict__ out) {
  const int bs = blockIdx.x;
  const int b = bs >> 11, s = bs & (S - 1);
  const int tid = threadIdx.x;
  __shared__ __align__(16) float pooled[DK];
  if (tid < DK) {
    const float* hb = heads + ((size_t)(b * H) * S + s) * DK + tid;
    float acc = 0.f;
#pragma unroll
    for (int hh = 0; hh < H; ++hh) acc += hb[(size_t)hh * S * DK];
    pooled[tid] = acc * 0.25f;
  }
  __syncthreads();
  const float4* wh4 = (const float4*)(Wh + (size_t)tid * DK);
  const float4* p4 = (const float4*)pooled;
  float4 av = {0.f, 0.f, 0.f, 0.f};
#pragma unroll
  for (int i = 0; i < DK / 4; ++i) {
    float4 w = wh4[i], p = p4[i];
    av.x = fmaf(w.x, p.x, av.x); av.y = fmaf(w.y, p.y, av.y);
    av.z = fmaf(w.z, p.z, av.z); av.w = fmaf(w.w, p.w, av.w);
  }
  out[(size_t)bs * DM + tid] = (av.x + av.y) + (av.z + av.w);
}

extern "C" void kernel_launch(void* const* d_in, const int* in_sizes, int n_in,
                              void* d_out, int out_size, void* d_ws, size_t ws_size,
                              hipStream_t stream) {
  const float* q = (const float*)d_in[0];
  const float* k = (const float*)d_in[1];
  const float* v = (const float*)d_in[2];
  const float* Wq = (const float*)d_in[3];
  const float* Wk = (const float*)d_in[4];
  const float* Wv = (const float*)d_in[5];
  const float* Wh = (const float*)d_in[6];

  float* out = (float*)d_out;                  // [B,S,DM]
  float* attn_out = out + (size_t)B * S * DM;  // [B,S,H,S]

  const size_t n1 = (size_t)B * H * S * DK;  // 2,097,152
  ushort* qhi = (ushort*)d_ws;
  ushort* qlo = qhi + n1;
  ushort* khi = qlo + n1;
  ushort* klo = khi + n1;
  ushort* vT = klo + n1;                              // B*DK*S
  float* heads = (float*)(vT + (size_t)B * DK * S);   // [B,H,S,DK] fp32
  ushort* wqh = (ushort*)(heads + n1);                // 65536 each
  ushort* wql = wqh + (size_t)H * DK * DM;
  ushort* wkh = wql + (size_t)H * DK * DM;
  ushort* wkl = wkh + (size_t)H * DK * DM;
  ushort* wvh = wkl + (size_t)H * DK * DM;            // 16384 each
  ushort* wvl = wvh + (size_t)DK * DM;

  wsplit_kernel<<<576, 256, 0, stream>>>(Wq, Wk, Wv, wqh, wql, wkh, wkl, wvh, wvl);
  proj_qk<0><<<512, 256, 0, stream>>>(q, wqh, wql, qhi, qlo);
  proj_qk<1><<<512, 256, 0, stream>>>(k, wkh, wkl, khi, klo);
  proj_v<<<128, 256, 0, stream>>>(v, wvh, wvl, vT);
  attn_kernel<<<B * H * S / 16, 256, 0, stream>>>(qhi, qlo, khi, klo, vT, attn_out, heads);
  out_kernel<<<B * S, 256, 0, stream>>>(heads, Wh, out);
}

// Round 6
// 373.507 us; speedup vs baseline: 9.9359x; 1.1342x over previous
//
#include <hip/hip_runtime.h>
#include <hip/hip_bf16.h>
#include <math.h>

#define B 4
#define S 2048
#define H 4
#define DK 64
#define DM 256

using bf16x8 = __attribute__((ext_vector_type(8))) short;
using bf16x4 = __attribute__((ext_vector_type(4))) short;
using f32x4 = __attribute__((ext_vector_type(4))) float;

__device__ inline ushort f2b(float f) {
  __hip_bfloat16 h = __float2bfloat16(f);
  ushort u; __builtin_memcpy(&u, &h, 2); return u;
}
__device__ inline float b2f(ushort u) {
  __hip_bfloat16 h; __builtin_memcpy(&h, &u, 2); return __bfloat162float(h);
}
__device__ inline float b2f_s(short s) { return b2f((ushort)s); }
__device__ inline bf16x8 ld8(const ushort* p) {
  return *reinterpret_cast<const bf16x8*>(p);
}
__device__ inline bf16x4 ld4(const ushort* p) {
  return *reinterpret_cast<const bf16x4*>(p);
}
#define MFMA(a, b, c) __builtin_amdgcn_mfma_f32_16x16x32_bf16((a), (b), (c), 0, 0, 0)

#if __has_builtin(__builtin_amdgcn_mfma_f32_16x16x16bf16_1k)
__device__ inline f32x4 MFMA16(bf16x4 a, bf16x4 b, f32x4 c) {
  return __builtin_amdgcn_mfma_f32_16x16x16bf16_1k(a, b, c, 0, 0, 0);
}
#else
__device__ inline f32x4 MFMA16(bf16x4 a, bf16x4 b, f32x4 c) {
  asm("v_mfma_f32_16x16x16_bf16 %0, %1, %2, %0" : "+v"(c) : "v"(a), "v"(b));
  return c;
}
#endif

// ---------------------------------------------------------------------------
// K0: split projection weights into bf16 hi/lo (once per call; 576 rows).
// ---------------------------------------------------------------------------
__global__ __launch_bounds__(256) void wsplit_kernel(
    const float* __restrict__ Wq, const float* __restrict__ Wk,
    const float* __restrict__ Wv,
    ushort* __restrict__ wqh, ushort* __restrict__ wql,
    ushort* __restrict__ wkh, ushort* __restrict__ wkl,
    ushort* __restrict__ wvh, ushort* __restrict__ wvl) {
  const int row = blockIdx.x;  // 0..575
  const int t = threadIdx.x;   // k
  const float* src; ushort* dh; ushort* dl; int r;
  if (row < 256) { src = Wq; dh = wqh; dl = wql; r = row; }
  else if (row < 512) { src = Wk; dh = wkh; dl = wkl; r = row - 256; }
  else { src = Wv; dh = wvh; dl = wvl; r = row - 512; }
  const float v = src[(size_t)r * DM + t];
  const ushort hi = f2b(v);
  dh[(size_t)r * DM + t] = hi;
  dl[(size_t)r * DM + t] = f2b(v - b2f(hi));
}

// ---------------------------------------------------------------------------
// K1a: q/k projection GEMM, split-bf16. Grid = head*128 + tile (512 blocks).
// ---------------------------------------------------------------------------
template <int SRC>  // 0=q, 1=k
__global__ __launch_bounds__(256) void proj_qk(
    const float* __restrict__ x, const ushort* __restrict__ wh,
    const ushort* __restrict__ wl,
    ushort* __restrict__ ohi, ushort* __restrict__ olo) {
  const int tile = blockIdx.x & 127;
  const int h = blockIdx.x >> 7;
  const int wid = threadIdx.x >> 6;
  const int lane = threadIdx.x & 63;
  const int l15 = lane & 15, g = lane >> 4;
  const int row0 = tile * 64 + wid * 16;

  bf16x8 ah[8], al[8];
  const float* xrow = x + (size_t)(row0 + l15) * DM;
#pragma unroll
  for (int ks = 0; ks < 8; ++ks) {
    float4 f0 = *(const float4*)(xrow + ks * 32 + 8 * g);
    float4 f1 = *(const float4*)(xrow + ks * 32 + 8 * g + 4);
    float fv[8] = {f0.x, f0.y, f0.z, f0.w, f1.x, f1.y, f1.z, f1.w};
    bf16x8 h8, l8;
#pragma unroll
    for (int j = 0; j < 8; ++j) {
      ushort hu = f2b(fv[j]);
      h8[j] = (short)hu;
      l8[j] = (short)f2b(fv[j] - b2f(hu));
    }
    ah[ks] = h8; al[ks] = l8;
  }

  f32x4 acc[4];
#pragma unroll
  for (int n = 0; n < 4; ++n) acc[n] = (f32x4){0.f, 0.f, 0.f, 0.f};

#pragma unroll
  for (int n = 0; n < 4; ++n) {
    const ushort* wrh = wh + (size_t)(h * DK + n * 16 + l15) * DM + 8 * g;
    const ushort* wrl = wl + (size_t)(h * DK + n * 16 + l15) * DM + 8 * g;
#pragma unroll
    for (int ks = 0; ks < 8; ++ks) {
      bf16x8 bh = ld8(wrh + ks * 32);
      bf16x8 bl = ld8(wrl + ks * 32);
      acc[n] = MFMA(ah[ks], bh, acc[n]);
      acc[n] = MFMA(al[ks], bh, acc[n]);
      acc[n] = MFMA(ah[ks], bl, acc[n]);
    }
  }

#pragma unroll
  for (int n = 0; n < 4; ++n) {
    const int e = n * 16 + l15;
#pragma unroll
    for (int r = 0; r < 4; ++r) {
      const int tok = row0 + 4 * g + r;
      const int b = tok >> 11, s = tok & (S - 1);
      const size_t idx = ((size_t)((b * H + h) * S + s)) * DK + e;
      const float val = acc[n][r];
      const ushort hu = f2b(val);
      ohi[idx] = hu;
      olo[idx] = f2b(val - b2f(hu));
    }
  }
}

// ---------------------------------------------------------------------------
// K1b: v projection GEMM (shared across heads), NF=4, grid 128.
// ---------------------------------------------------------------------------
__global__ __launch_bounds__(256) void proj_v(
    const float* __restrict__ x, const ushort* __restrict__ wh,
    const ushort* __restrict__ wl, ushort* __restrict__ vT) {
  const int wid = threadIdx.x >> 6;
  const int lane = threadIdx.x & 63;
  const int l15 = lane & 15, g = lane >> 4;
  const int row0 = blockIdx.x * 64 + wid * 16;

  bf16x8 ah[8], al[8];
  const float* xrow = x + (size_t)(row0 + l15) * DM;
#pragma unroll
  for (int ks = 0; ks < 8; ++ks) {
    float4 f0 = *(const float4*)(xrow + ks * 32 + 8 * g);
    float4 f1 = *(const float4*)(xrow + ks * 32 + 8 * g + 4);
    float fv[8] = {f0.x, f0.y, f0.z, f0.w, f1.x, f1.y, f1.z, f1.w};
    bf16x8 h8, l8;
#pragma unroll
    for (int j = 0; j < 8; ++j) {
      ushort hu = f2b(fv[j]);
      h8[j] = (short)hu;
      l8[j] = (short)f2b(fv[j] - b2f(hu));
    }
    ah[ks] = h8; al[ks] = l8;
  }

  f32x4 acc[4];
#pragma unroll
  for (int n = 0; n < 4; ++n) acc[n] = (f32x4){0.f, 0.f, 0.f, 0.f};
#pragma unroll
  for (int n = 0; n < 4; ++n) {
    const ushort* wrh = wh + (size_t)(n * 16 + l15) * DM + 8 * g;
    const ushort* wrl = wl + (size_t)(n * 16 + l15) * DM + 8 * g;
#pragma unroll
    for (int ks = 0; ks < 8; ++ks) {
      bf16x8 bh = ld8(wrh + ks * 32);
      bf16x8 bl = ld8(wrl + ks * 32);
      acc[n] = MFMA(ah[ks], bh, acc[n]);
      acc[n] = MFMA(al[ks], bh, acc[n]);
      acc[n] = MFMA(ah[ks], bl, acc[n]);
    }
  }
#pragma unroll
  for (int n = 0; n < 4; ++n) {
    const int e = n * 16 + l15;
#pragma unroll
    for (int r = 0; r < 4; ++r) {
      const int tok = row0 + 4 * g + r;
      const int b = tok >> 11, s = tok & (S - 1);
      vT[((size_t)b * DK + e) * S + s] = f2b(acc[n][r]);
    }
  }
}

// ---------------------------------------------------------------------------
// K2: attention, swapped MFMA, key-split across 4 waves, SINGLE sweep.
// Per chunk: 3-term QK^T scores -> unnormalized P' = exp(s*SC) -> (a) bf16 P'
// into XOR-swizzled LDS row buffer, (b) per-lane ssum, (c) unnormalized PV
// accumulate. After the loop: block-combine ssum -> inv; FLUSH attn rows from
// LDS as contiguous 1KB stores (x inv); combine PV partials (LDS reused) and
// write heads (x inv). Dynamic LDS 64KB -> 2 blocks/CU.
// ---------------------------------------------------------------------------
__global__ __launch_bounds__(256) void attn_kernel(
    const ushort* __restrict__ qhi, const ushort* __restrict__ qlo,
    const ushort* __restrict__ khi, const ushort* __restrict__ klo,
    const ushort* __restrict__ vT,
    float* __restrict__ attn_out, float* __restrict__ heads) {
  extern __shared__ __align__(16) ushort pb[];  // [4 waves][16 rows][512]
  __shared__ float ssum_sh[4][16];
  __shared__ float inv_sh[16];
  const int wid = threadIdx.x >> 6;
  const int lane = threadIdx.x & 63;
  const int l15 = lane & 15, g = lane >> 4;
  const int tid = threadIdx.x;
  const int bid = blockIdx.x;
  // XCD swizzle: 2048 blocks, XCD x serves swz in [x*256, x*256+256)
  const int swz = (bid & 7) * 256 + (bid >> 3);
  const int st = swz & 127;
  const int h = (swz >> 7) & 3;
  const int b = swz >> 9;
  const int row0 = st * 16;
  const float SC = 0.125f;  // 1/sqrt(64)
  const int t_lo = wid * 512;

  const size_t bh = (size_t)(b * H + h);
  const ushort* qbh = qhi + (bh * S + row0 + l15) * DK;
  const ushort* qbl = qlo + (bh * S + row0 + l15) * DK;
  const bf16x8 aqh0 = ld8(qbh + 8 * g), aqh1 = ld8(qbh + 32 + 8 * g);
  const bf16x8 aql0 = ld8(qbl + 8 * g), aql1 = ld8(qbl + 32 + 8 * g);
  const ushort* kbh = khi + bh * S * DK;
  const ushort* kbl = klo + bh * S * DK;
  const ushort* vb_b = vT + (size_t)b * DK * S;

  ushort* pw = pb + (size_t)(wid * 16 + l15) * 512;  // P' row for q = l15
  const int csw = (l15 & 7) << 3;                    // XOR swizzle (8-elem units)

  float ssum = 0.f;
  f32x4 hacc[4] = {{0.f, 0.f, 0.f, 0.f}, {0.f, 0.f, 0.f, 0.f},
                   {0.f, 0.f, 0.f, 0.f}, {0.f, 0.f, 0.f, 0.f}};

  for (int tt = 0; tt < 512; tt += 32) {
    const int t0 = t_lo + tt;
    const ushort* kh_ = kbh + (size_t)(t0 + l15) * DK + 8 * g;
    const ushort* kl_ = kbl + (size_t)(t0 + l15) * DK + 8 * g;
    bf16x8 bh0 = ld8(kh_), bh1 = ld8(kh_ + 32);
    bf16x8 bl0 = ld8(kl_), bl1 = ld8(kl_ + 32);
    bf16x8 ch0 = ld8(kh_ + 16 * DK), ch1 = ld8(kh_ + 16 * DK + 32);
    bf16x8 cl0 = ld8(kl_ + 16 * DK), cl1 = ld8(kl_ + 16 * DK + 32);
    f32x4 acc0 = {0.f, 0.f, 0.f, 0.f}, acc1 = {0.f, 0.f, 0.f, 0.f};
    acc0 = MFMA(bh0, aqh0, acc0); acc0 = MFMA(bh1, aqh1, acc0);
    acc0 = MFMA(bl0, aqh0, acc0); acc0 = MFMA(bl1, aqh1, acc0);
    acc0 = MFMA(bh0, aql0, acc0); acc0 = MFMA(bh1, aql1, acc0);
    acc1 = MFMA(ch0, aqh0, acc1); acc1 = MFMA(ch1, aqh1, acc1);
    acc1 = MFMA(cl0, aqh0, acc1); acc1 = MFMA(cl1, aqh1, acc1);
    acc1 = MFMA(ch0, aql0, acc1); acc1 = MFMA(ch1, aql1, acc1);

    const float p0 = __expf(acc0[0] * SC);
    const float p1 = __expf(acc0[1] * SC);
    const float p2 = __expf(acc0[2] * SC);
    const float p3 = __expf(acc0[3] * SC);
    const float p4 = __expf(acc1[0] * SC);
    const float p5 = __expf(acc1[1] * SC);
    const float p6 = __expf(acc1[2] * SC);
    const float p7 = __expf(acc1[3] * SC);
    ssum += ((p0 + p1) + (p2 + p3)) + ((p4 + p5) + (p6 + p7));

    bf16x4 pa0, pa1;
    pa0[0] = (short)f2b(p0); pa0[1] = (short)f2b(p1);
    pa0[2] = (short)f2b(p2); pa0[3] = (short)f2b(p3);
    pa1[0] = (short)f2b(p4); pa1[1] = (short)f2b(p5);
    pa1[2] = (short)f2b(p6); pa1[3] = (short)f2b(p7);

    // stash unnormalized bf16 P' (swizzled, 2-way-max bank usage)
    *(bf16x4*)(pw + ((tt + 4 * g) ^ csw)) = pa0;
    *(bf16x4*)(pw + ((tt + 16 + 4 * g) ^ csw)) = pa1;

    // unnormalized PV accumulate
#pragma unroll
    for (int n = 0; n < 4; ++n) {
      bf16x4 vb0 = ld4(vb_b + (size_t)(n * 16 + l15) * S + t0 + 4 * g);
      bf16x4 vb1 = ld4(vb_b + (size_t)(n * 16 + l15) * S + t0 + 16 + 4 * g);
      hacc[n] = MFMA16(pa0, vb0, hacc[n]);
      hacc[n] = MFMA16(pa1, vb1, hacc[n]);
    }
  }
  ssum += __shfl_xor(ssum, 16, 64);
  ssum += __shfl_xor(ssum, 32, 64);
  if (g == 0) ssum_sh[wid][l15] = ssum;
  __syncthreads();
  if (tid < 16)
    inv_sh[tid] = 1.f / (ssum_sh[0][tid] + ssum_sh[1][tid] +
                         ssum_sh[2][tid] + ssum_sh[3][tid]);
  __syncthreads();

  // ---- flush attn: 16 rows x 512-key slice; 1KB-contiguous stores ----
  {
    float* abase = attn_out + (((size_t)(b * S + row0)) * H + h) * S + t_lo;
#pragma unroll 4
    for (int r = 0; r < 16; ++r) {
      const ushort* prow = pb + (size_t)(wid * 16 + r) * 512;
      const int rsw = (r & 7) << 3;
      bf16x4 a0 = *(const bf16x4*)(prow + ((4 * lane) ^ rsw));
      bf16x4 a1 = *(const bf16x4*)(prow + ((256 + 4 * lane) ^ rsw));
      const float inv = inv_sh[r];
      float4 o0 = {b2f_s(a0[0]) * inv, b2f_s(a0[1]) * inv,
                   b2f_s(a0[2]) * inv, b2f_s(a0[3]) * inv};
      float4 o1 = {b2f_s(a1[0]) * inv, b2f_s(a1[1]) * inv,
                   b2f_s(a1[2]) * inv, b2f_s(a1[3]) * inv};
      float* dst = abase + (size_t)r * (H * S);
      *(float4*)(dst + 4 * lane) = o0;
      *(float4*)(dst + 256 + 4 * lane) = o1;
    }
  }
  __syncthreads();  // pbuf free -> reuse as hpart [4][16][64] f32

  float* hp = (float*)pb;
#pragma unroll
  for (int n = 0; n < 4; ++n)
#pragma unroll
    for (int r = 0; r < 4; ++r)
      hp[(size_t)(wid * 16 + 4 * g + r) * 64 + n * 16 + l15] = hacc[n][r];
  __syncthreads();
#pragma unroll
  for (int i = 0; i < 4; ++i) {
    const int e = tid + i * 256;  // 0..1023
    const int row = e >> 6, dim = e & 63;
    const float sum = hp[(size_t)row * 64 + dim] + hp[(size_t)(16 + row) * 64 + dim] +
                      hp[(size_t)(32 + row) * 64 + dim] + hp[(size_t)(48 + row) * 64 + dim];
    heads[(bh * S + row0 + row) * DK + dim] = sum * inv_sh[row];
  }
}

// ---------------------------------------------------------------------------
// K3: mean over heads + output projection. One block per (b,s) token.
// ---------------------------------------------------------------------------
__global__ __launch_bounds__(256) void out_kernel(
    const float* __restrict__ heads, const float* __restrict__ Wh,
    float* __restrict__ out) {
  const int bs = blockIdx.x;
  const int b = bs >> 11, s = bs & (S - 1);
  const int tid = threadIdx.x;
  __shared__ __align__(16) float pooled[DK];
  if (tid < DK) {
    const float* hb = heads + ((size_t)(b * H) * S + s) * DK + tid;
    float acc = 0.f;
#pragma unroll
    for (int hh = 0; hh < H; ++hh) acc += hb[(size_t)hh * S * DK];
    pooled[tid] = acc * 0.25f;
  }
  __syncthreads();
  const float4* wh4 = (const float4*)(Wh + (size_t)tid * DK);
  const float4* p4 = (const float4*)pooled;
  float4 av = {0.f, 0.f, 0.f, 0.f};
#pragma unroll
  for (int i = 0; i < DK / 4; ++i) {
    float4 w = wh4[i], p = p4[i];
    av.x = fmaf(w.x, p.x, av.x); av.y = fmaf(w.y, p.y, av.y);
    av.z = fmaf(w.z, p.z, av.z); av.w = fmaf(w.w, p.w, av.w);
  }
  out[(size_t)bs * DM + tid] = (av.x + av.y) + (av.z + av.w);
}

extern "C" void kernel_launch(void* const* d_in, const int* in_sizes, int n_in,
                              void* d_out, int out_size, void* d_ws, size_t ws_size,
                              hipStream_t stream) {
  const float* q = (const float*)d_in[0];
  const float* k = (const float*)d_in[1];
  const float* v = (const float*)d_in[2];
  const float* Wq = (const float*)d_in[3];
  const float* Wk = (const float*)d_in[4];
  const float* Wv = (const float*)d_in[5];
  const float* Wh = (const float*)d_in[6];

  float* out = (float*)d_out;                  // [B,S,DM]
  float* attn_out = out + (size_t)B * S * DM;  // [B,S,H,S]

  const size_t n1 = (size_t)B * H * S * DK;  // 2,097,152
  ushort* qhi = (ushort*)d_ws;
  ushort* qlo = qhi + n1;
  ushort* khi = qlo + n1;
  ushort* klo = khi + n1;
  ushort* vT = klo + n1;                              // B*DK*S
  float* heads = (float*)(vT + (size_t)B * DK * S);   // [B,H,S,DK] fp32
  ushort* wqh = (ushort*)(heads + n1);                // 65536 each
  ushort* wql = wqh + (size_t)H * DK * DM;
  ushort* wkh = wql + (size_t)H * DK * DM;
  ushort* wkl = wkh + (size_t)H * DK * DM;
  ushort* wvh = wkl + (size_t)H * DK * DM;            // 16384 each
  ushort* wvl = wvh + (size_t)DK * DM;

  wsplit_kernel<<<576, 256, 0, stream>>>(Wq, Wk, Wv, wqh, wql, wkh, wkl, wvh, wvl);
  proj_qk<0><<<512, 256, 0, stream>>>(q, wqh, wql, qhi, qlo);
  proj_qk<1><<<512, 256, 0, stream>>>(k, wkh, wkl, khi, klo);
  proj_v<<<128, 256, 0, stream>>>(v, wvh, wvl, vT);
  attn_kernel<<<B * H * S / 16, 256, 65536, stream>>>(qhi, qlo, khi, klo, vT,
                                                      attn_out, heads);
  out_kernel<<<B * S, 256, 0, stream>>>(heads, Wh, out);
}